// Round 3
// baseline (13853.806 us; speedup 1.0000x reference)
//
#include <hip/hip_runtime.h>
#include <hip/hip_bf16.h>
#include <cstdint>
#include <cstddef>

#define DEV static __device__ __forceinline__

typedef unsigned short u16;
typedef __attribute__((ext_vector_type(8))) short short8;
typedef __attribute__((ext_vector_type(4))) short short4v;
typedef __attribute__((ext_vector_type(4))) float f32x4;

constexpr int B = 64, S = 1024, DIN = 256, H = 512;
constexpr int BS = B * S;

DEV float b2f(u16 u) { union { unsigned int i; float f; } v; v.i = ((unsigned int)u) << 16; return v.f; }
DEV u16 f2u(float f) {
  __hip_bfloat16 h = __float2bfloat16(f);
  u16 r; __builtin_memcpy(&r, &h, 2); return r;
}
DEV float sigf(float x) { return 1.0f / (1.0f + __expf(-x)); }
// dataset load: isf=1 -> float32, else bf16
DEV float ldf(const void* p, size_t i, int isf) {
  return isf ? ((const float*)p)[i] : b2f(((const u16*)p)[i]);
}

DEV void gload_lds16(const void* g, void* l) {
  __builtin_amdgcn_global_load_lds(
      (const __attribute__((address_space(1))) unsigned int*)g,
      (__attribute__((address_space(3))) unsigned int*)l, 16, 0, 0);
}

// ---------------- dtype detect: ln_g[0]==1.0; f32 -> low u16 is 0 ----------------
__global__ void detect_kernel(const u16* __restrict__ g, int* __restrict__ flag) {
  if (threadIdx.x == 0) flag[0] = (g[0] == (u16)0) ? 1 : 0;
}

// ---------------- LayerNorm: xn = LN(seq)*g + b (bf16 out) ----------------
__global__ __launch_bounds__(256) void ln_kernel(const void* __restrict__ x,
    const void* __restrict__ gw, const void* __restrict__ bw, u16* __restrict__ xn,
    const int* __restrict__ dfl) {
  int isf = dfl[0];
  int tid = threadIdx.x, lane = tid & 63, wid = tid >> 6;
  size_t t = (size_t)blockIdx.x * 4 + wid;  // token
  float f[4];
  if (isf) {
    f32x4 v = *(const f32x4*)((const float*)x + t * DIN + lane * 4);
#pragma unroll
    for (int j = 0; j < 4; j++) f[j] = v[j];
  } else {
    short4v v = *(const short4v*)((const u16*)x + t * DIN + lane * 4);
#pragma unroll
    for (int j = 0; j < 4; j++) f[j] = b2f((u16)v[j]);
  }
  float s0 = f[0] + f[1] + f[2] + f[3];
  float s1 = f[0]*f[0] + f[1]*f[1] + f[2]*f[2] + f[3]*f[3];
#pragma unroll
  for (int off = 32; off; off >>= 1) { s0 += __shfl_xor(s0, off); s1 += __shfl_xor(s1, off); }
  float mu = s0 * (1.0f / DIN);
  float var = s1 * (1.0f / DIN) - mu * mu;
  float rs = rsqrtf(var + 1e-5f);
  short4v o;
#pragma unroll
  for (int j = 0; j < 4; j++) {
    float xv = (f[j] - mu) * rs * ldf(gw, lane*4 + j, isf) + ldf(bw, lane*4 + j, isf);
    o[j] = (short)f2u(xv);
  }
  *(short4v*)(xn + t * DIN + lane * 4) = o;
}

// ---------------- transpose (K,N) -> (N,K), dataset in -> bf16 out ----------------
__global__ void transpose_kernel(const void* __restrict__ in, u16* __restrict__ out,
                                 int R, int C, const int* __restrict__ dfl) {
  int isf = dfl[0];
  int idx = blockIdx.x * 256 + threadIdx.x;
  if (idx >= R * C) return;
  int r = idx / C, c = idx - r * C;
  out[(size_t)c * R + r] = isf ? f2u(((const float*)in)[idx]) : ((const u16*)in)[idx];
}

// ---------------- dataset -> bf16 cast (8 elems/thread) ----------------
__global__ __launch_bounds__(256) void cast_kernel(const void* __restrict__ in,
    u16* __restrict__ out, int n, const int* __restrict__ dfl) {
  int isf = dfl[0];
  int i0 = (blockIdx.x * 256 + threadIdx.x) * 8;
  if (i0 >= n) return;
  short8 o;
  if (isf) {
    f32x4 a = *(const f32x4*)((const float*)in + i0);
    f32x4 b = *(const f32x4*)((const float*)in + i0 + 4);
#pragma unroll
    for (int j = 0; j < 4; j++) { o[j] = (short)f2u(a[j]); o[j+4] = (short)f2u(b[j]); }
  } else {
    o = *(const short8*)((const u16*)in + i0);
  }
  *(short8*)(out + i0) = o;
}

// ---------------- depthwise conv3 along S + bc ----------------
__global__ __launch_bounds__(256) void conv_kernel(const u16* __restrict__ h0,
    const void* __restrict__ Wc, const void* __restrict__ bc, u16* __restrict__ hid,
    const int* __restrict__ dfl) {
  int isf = dfl[0];
  int tid = threadIdx.x;
  size_t token = (size_t)blockIdx.x * 4 + (tid >> 6);
  int lane = tid & 63;
  int s = (int)(token & (size_t)(S - 1));
  int hh = lane * 8;
  const u16* pm = h0 + token * H + hh;
  short8 vm = *(const short8*)pm;
  short8 vp = {0,0,0,0,0,0,0,0}, vn = {0,0,0,0,0,0,0,0};
  if (s > 0) vp = *(const short8*)(pm - H);
  if (s < S - 1) vn = *(const short8*)(pm + H);
  float w[24];
#pragma unroll
  for (int j = 0; j < 24; j++) w[j] = ldf(Wc, (size_t)hh * 3 + j, isf);
  short8 vo;
#pragma unroll
  for (int i = 0; i < 8; i++) {
    float acc = ldf(bc, hh + i, isf);
    acc += b2f((u16)vp[i]) * w[i*3 + 0];
    acc += b2f((u16)vm[i]) * w[i*3 + 1];
    acc += b2f((u16)vn[i]) * w[i*3 + 2];
    vo[i] = (short)f2u(acc);
  }
  *(short8*)(hid + token * H + hh) = vo;
}

// ---------------- generic MFMA GEMM: C(BSx512) = A(BSxK) @ Bt^T, +bias(+res) ----------------
DEV int swz(int row, int kbyte) { return row * 128 + (kbyte ^ ((row & 7) << 4)); }

__global__ __launch_bounds__(256) void gemm_kernel(
    const u16* __restrict__ A, const u16* __restrict__ Bt,
    const void* __restrict__ bias, const u16* __restrict__ res,
    void* __restrict__ C, int K, const int* __restrict__ dfl, int out_ds) {
  int isf = dfl[0];
  __shared__ __align__(16) char sA[128 * 64 * 2];
  __shared__ __align__(16) char sB[128 * 64 * 2];
  int tid = threadIdx.x, lane = tid & 63, wid = tid >> 6;
  int wr = wid >> 1, wc = wid & 1;
  int m0 = blockIdx.y * 128, n0 = blockIdx.x * 128;
  f32x4 zf = {0.f, 0.f, 0.f, 0.f};
  f32x4 acc[4][4];
#pragma unroll
  for (int a = 0; a < 4; a++)
#pragma unroll
    for (int b = 0; b < 4; b++) acc[a][b] = zf;
  int nsteps = K >> 6;
  for (int kt = 0; kt < nsteps; kt++) {
    int k0 = kt << 6;
    __syncthreads();
#pragma unroll
    for (int ri = 0; ri < 4; ri++) {
      int ci = ri * 256 + tid;
      int row = ci >> 3, kc = ci & 7;
      *(short8*)(sA + swz(row, kc * 16)) = *(const short8*)(A + (size_t)(m0 + row) * K + k0 + kc * 8);
      *(short8*)(sB + swz(row, kc * 16)) = *(const short8*)(Bt + (size_t)(n0 + row) * K + k0 + kc * 8);
    }
    __syncthreads();
#pragma unroll
    for (int kk = 0; kk < 2; kk++) {
      int kb = (kk * 32 + ((lane >> 4) * 8)) * 2;
      short8 af[4], bf[4];
#pragma unroll
      for (int t = 0; t < 4; t++) af[t] = *(const short8*)(sA + swz(wr * 64 + t * 16 + (lane & 15), kb));
#pragma unroll
      for (int t = 0; t < 4; t++) bf[t] = *(const short8*)(sB + swz(wc * 64 + t * 16 + (lane & 15), kb));
#pragma unroll
      for (int tr = 0; tr < 4; tr++)
#pragma unroll
        for (int tc = 0; tc < 4; tc++)
          acc[tr][tc] = __builtin_amdgcn_mfma_f32_16x16x32_bf16(af[tr], bf[tc], acc[tr][tc], 0, 0, 0);
    }
  }
#pragma unroll
  for (int tr = 0; tr < 4; tr++) {
#pragma unroll
    for (int tc = 0; tc < 4; tc++) {
      int n = n0 + wc * 64 + tc * 16 + (lane & 15);
      float bv = ldf(bias, n, isf);
#pragma unroll
      for (int jj = 0; jj < 4; jj++) {
        int m = m0 + wr * 64 + tr * 16 + ((lane >> 4) * 4) + jj;
        size_t idx = (size_t)m * 512 + n;
        float v = acc[tr][tc][jj] + bv;
        if (res) v += b2f(res[idx]);
        if (out_ds && isf) ((float*)C)[idx] = v;
        else ((u16*)C)[idx] = f2u(v);
      }
    }
  }
}

// ---------------- persistent sequential recurrence ----------------
// grid 256 = 4 rowgroups(16 batch rows) x 64 colblocks(8 cols of H)
__global__ __launch_bounds__(256, 1) void seq_kernel(
    const u16* __restrict__ hid, const u16* __restrict__ qe, const int* __restrict__ mask,
    const void* __restrict__ Wmw, const void* __restrict__ bmw,
    const void* __restrict__ Wmc, const void* __restrict__ bmc,
    const void* __restrict__ Wow, const void* __restrict__ bow,
    const void* __restrict__ Woc, const void* __restrict__ boc,
    const void* __restrict__ Wrw, const void* __restrict__ brw,
    const void* __restrict__ Wrc, const void* __restrict__ brc,
    u16* __restrict__ hist, void* __restrict__ dout, unsigned int* __restrict__ ctr,
    const int* __restrict__ dfl) {

  constexpr int PITCHA = (1024 + 8) * 2;   // x,q rows (bytes)
  constexpr int PITCHB = (1536 + 8) * 2;   // m,o,r rows (bytes)
  constexpr int RED_OFF = 49408;
  constexpr int ST_OFF = RED_OFF + 12288;
  constexpr int BIAS_OFF = ST_OFF + 1536;
  constexpr int MASK_OFF = BIAS_OFF + 192;
  constexpr int DEAD_OFF = MASK_OFF + 64;
  __shared__ __align__(16) char lds_raw[DEAD_OFF + 16];

  float* REDf = (float*)(lds_raw + RED_OFF);
  float* STf = (float*)(lds_raw + ST_OFF);
  float* BIASf = (float*)(lds_raw + BIAS_OFF);
  int* MASKi = (int*)(lds_raw + MASK_OFF);
  int* DEADi = (int*)(lds_raw + DEAD_OFF);

  int isf = dfl[0];
  int tid = threadIdx.x, lane = tid & 63, wid = tid >> 6;
  int g = blockIdx.x >> 6, cb = blockIdx.x & 63;
  int b0 = g * 16, c0 = cb * 8;

  // section -> tiles; tiles: T0=mw|ow, T1=mc|oc, T2=rw|rc ; sections: x,q,m,o,r
  constexpr int NTS[5] = {3, 3, 3, 2, 1};
  constexpr int FBASE[5] = {0, 12, 24, 36, 44};
  constexpr int TLIST[5][3] = { {0,1,2}, {0,1,2}, {0,1,2}, {1,2,0}, {1,0,0} };
  // (tile, sec, half) -> weight selector / row offset ; -1 = zero
  constexpr int WSEL[3][5][2] = {
    { {0,-1}, {0,2}, {-1,2}, {-1,-1}, {-1,-1} },
    { {1,-1}, {1,3}, {-1,3}, {1,-1}, {-1,3} },
    { {-1,5}, {4,-1}, {-1,5}, {4,5}, {-1,-1} },
  };
  constexpr int ROFF[3][5][2] = {
    { {0,0}, {512,0}, {0,512}, {0,0}, {0,0} },
    { {0,0}, {512,0}, {0,512}, {1024,0}, {0,1024} },
    { {0,0}, {0,0}, {0,512}, {512,1024}, {0,0} },
  };

  // ---- load weight B-fragments into VGPRs (once) ----
  short8 wfrag[48];
  {
    int col16 = lane & 15, half = col16 >> 3;
    int coln = c0 + (col16 & 7);
#pragma unroll
    for (int sec = 0; sec < 5; sec++) {
#pragma unroll
      for (int j = 0; j < 4; j++) {
#pragma unroll
        for (int ti = 0; ti < 3; ti++) {
          if (ti >= NTS[sec]) continue;
          const int tile = TLIST[sec][ti];
          int wsel = WSEL[tile][sec][half];
          int ro = ROFF[tile][sec][half];
          const void* wp = (wsel == 0) ? Wmw : (wsel == 1) ? Wmc : (wsel == 2) ? Wow
                         : (wsel == 3) ? Woc : (wsel == 4) ? Wrw : Wrc;
          short8 f8;
#pragma unroll
          for (int jj = 0; jj < 8; jj++) {
            int kin = (j * 4 + wid) * 32 + ((lane >> 4) * 8) + jj;
            u16 v = 0;
            if (wsel >= 0) v = f2u(ldf(wp, (size_t)(ro + kin) * 512 + coln, isf));
            f8[jj] = (short)v;
          }
          wfrag[FBASE[sec] + j * NTS[sec] + ti] = f8;
        }
      }
    }
  }
  // biases (order mw,mc,ow,oc,rw,rc) and state init
  if (tid < 48) {
    int gate = tid >> 3, col = tid & 7;
    const void* bp_ = (gate == 0) ? bmw : (gate == 1) ? bmc : (gate == 2) ? bow
                    : (gate == 3) ? boc : (gate == 4) ? brw : brc;
    BIASf[tid] = ldf(bp_, c0 + col, isf);
  }
  if (tid < 128) { STf[tid*3] = 0.f; STf[tid*3+1] = 0.f; STf[tid*3+2] = 0.f; }
  if (tid == 0) DEADi[0] = 0;
  __syncthreads();

  bool dead = false;
  for (int s = 0; s < S; s++) {
    // wait for step s-1 states from all 64 colblocks of this rowgroup
    if (tid == 0 && s > 0 && !dead) {
      unsigned int it = 0;
      while (__hip_atomic_load(&ctr[g * S + s - 1], __ATOMIC_ACQUIRE, __HIP_MEMORY_SCOPE_SYSTEM) < 64u) {
        __builtin_amdgcn_s_sleep(2);
        if (++it > (1u << 22)) { dead = true; DEADi[0] = 1; break; }
      }
      __threadfence_system();  // acquire: invalidate stale caches
    }
    __syncthreads();

    // ---- Phase A: stage x,q ----
    {
      int r0 = wid * 4;
#pragma unroll
      for (int rr = 0; rr < 4; rr++) {
        int b = b0 + r0 + rr;
        const u16* gx = hid + ((size_t)b * S + s) * H;
        const u16* gq = qe + ((size_t)b * S + s) * H;
        char* lx = lds_raw + (size_t)(r0 + rr) * PITCHA;
        gload_lds16(gx + lane * 8, lx);
        gload_lds16(gq + lane * 8, lx + 1024);
      }
    }
    if (tid < 16) MASKi[tid] = mask[(size_t)(b0 + tid) * S + s];
    asm volatile("s_waitcnt vmcnt(0)" ::: "memory");
    __syncthreads();

    f32x4 zf = {0.f, 0.f, 0.f, 0.f};
    f32x4 acc[3]; acc[0] = zf; acc[1] = zf; acc[2] = zf;

    // ---- Phase A MFMA: sections x,q ----
#pragma unroll
    for (int sec = 0; sec < 2; sec++) {
#pragma unroll
      for (int j = 0; j < 4; j++) {
        const short8 a = *(const short8*)(lds_raw + (size_t)(lane & 15) * PITCHA + sec * 1024 +
                                          ((j * 4 + wid) * 32 + ((lane >> 4) * 8)) * 2);
#pragma unroll
        for (int ti = 0; ti < 3; ti++) {
          if (ti >= NTS[sec]) continue;
          const int tile = TLIST[sec][ti];
          acc[tile] = __builtin_amdgcn_mfma_f32_16x16x32_bf16(a, wfrag[FBASE[sec] + j * NTS[sec] + ti], acc[tile], 0, 0, 0);
        }
      }
    }
    __syncthreads();  // U reads done -> safe to overwrite

    // ---- Phase B: stage m,o,r (bf16 exchange) ----
    if (s == 0) {
      short8 z8 = {0,0,0,0,0,0,0,0};
#pragma unroll
      for (int rr = 0; rr < 4; rr++) {
        char* lr = lds_raw + (size_t)(wid * 4 + rr) * PITCHB;
#pragma unroll
        for (int sc = 0; sc < 3; sc++)
          *(short8*)(lr + sc * 1024 + lane * 16) = z8;
      }
    } else {
#pragma unroll
      for (int rr = 0; rr < 4; rr++) {
        int b = b0 + wid * 4 + rr;
        const u16* gm = hist + ((size_t)b * S + (s - 1)) * 1536;
        char* lr = lds_raw + (size_t)(wid * 4 + rr) * PITCHB;
        gload_lds16(gm + lane * 8, lr);
        gload_lds16(gm + 512 + lane * 8, lr + 1024);
        gload_lds16(gm + 1024 + lane * 8, lr + 2048);
      }
      asm volatile("s_waitcnt vmcnt(0)" ::: "memory");
    }
    __syncthreads();

    // ---- Phase B MFMA: sections m,o,r ----
#pragma unroll
    for (int sec = 2; sec < 5; sec++) {
#pragma unroll
      for (int j = 0; j < 4; j++) {
        const short8 a = *(const short8*)(lds_raw + (size_t)(lane & 15) * PITCHB + (sec - 2) * 1024 +
                                          ((j * 4 + wid) * 32 + ((lane >> 4) * 8)) * 2);
#pragma unroll
        for (int ti = 0; ti < 3; ti++) {
          if (ti >= NTS[sec]) continue;
          const int tile = TLIST[sec][ti];
          acc[tile] = __builtin_amdgcn_mfma_f32_16x16x32_bf16(a, wfrag[FBASE[sec] + j * NTS[sec] + ti], acc[tile], 0, 0, 0);
        }
      }
    }
    // dump partials (lane-major)
#pragma unroll
    for (int t = 0; t < 3; t++)
      *(f32x4*)(REDf + (wid * 3 + t) * 256 + lane * 4) = acc[t];
    __syncthreads();

    // ---- finalize: reduce partials, gates, state update, publish bf16 ----
    if (tid < 128) {
      int row = tid >> 3, col = tid & 7;
      int lbase = ((row >> 2) * 16) * 4 + (row & 3);
      auto rd = [&](int tile, int col16) {
        int e = lbase + col16 * 4;
        return REDf[(0 * 3 + tile) * 256 + e] + REDf[(1 * 3 + tile) * 256 + e] +
               REDf[(2 * 3 + tile) * 256 + e] + REDf[(3 * 3 + tile) * 256 + e];
      };
      float pmw = rd(0, col)     + BIASf[0 * 8 + col];
      float pmc = rd(1, col)     + BIASf[1 * 8 + col];
      float pow_ = rd(0, col + 8) + BIASf[2 * 8 + col];
      float poc = rd(1, col + 8) + BIASf[3 * 8 + col];
      float prw = rd(2, col)     + BIASf[4 * 8 + col];
      float prc = rd(2, col + 8) + BIASf[5 * 8 + col];
      float mwv = sigf(pmw), mcv = tanhf(pmc);
      float owv = sigf(pow_), ocv = tanhf(poc);
      float rwv = sigf(prw), rcv = tanhf(prc);
      float* st = STf + (row * 8 + col) * 3;
      float m_ = st[0], o_ = st[1], r_ = st[2];
      bool v = MASKi[row] > 0;
      float nm = v ? (1.f - mwv) * m_ + mwv * mcv : m_;
      float no = v ? (1.f - owv) * o_ + owv * ocv : o_;
      float nr = v ? (1.f - rwv) * r_ + rwv * rcv : r_;
      if (DEADi[0]) { nm = 12345.0f; no = 12345.0f; nr = 12345.0f; }  // deadlock marker
      st[0] = nm; st[1] = no; st[2] = nr;
      size_t hb = ((size_t)(b0 + row) * S + s) * 1536 + c0 + col;
      // system-scope write-through: guarantees cross-XCD visibility once vmcnt retires
      __hip_atomic_store(&hist[hb], f2u(nm), __ATOMIC_RELAXED, __HIP_MEMORY_SCOPE_SYSTEM);
      __hip_atomic_store(&hist[hb + 512], f2u(no), __ATOMIC_RELAXED, __HIP_MEMORY_SCOPE_SYSTEM);
      __hip_atomic_store(&hist[hb + 1024], f2u(nr), __ATOMIC_RELAXED, __HIP_MEMORY_SCOPE_SYSTEM);
    }
    __syncthreads();  // includes vmcnt(0): stores globally visible
    if (tid == 0)
      __hip_atomic_fetch_add(&ctr[g * S + s], 1u, __ATOMIC_RELEASE, __HIP_MEMORY_SCOPE_SYSTEM);
  }

  // final states -> d_out tail (dataset dtype)
  if (tid < 128) {
    int row = tid >> 3, col = tid & 7;
    float* st = STf + (row * 8 + col) * 3;
    size_t bi = (size_t)(b0 + row) * H + c0 + col;
    size_t obase = (size_t)BS * 512;
    size_t BH = (size_t)B * H;
    if (isf) {
      float* p = (float*)dout;
      p[obase + bi] = st[0]; p[obase + BH + bi] = st[1]; p[obase + 2*BH + bi] = st[2];
    } else {
      u16* p = (u16*)dout;
      p[obase + bi] = f2u(st[0]); p[obase + BH + bi] = f2u(st[1]); p[obase + 2*BH + bi] = f2u(st[2]);
    }
  }
}

extern "C" void kernel_launch(void* const* d_in, const int* in_sizes, int n_in,
                              void* d_out, int out_size, void* d_ws, size_t ws_size,
                              hipStream_t stream) {
  (void)in_sizes; (void)n_in;
  const void* seq = d_in[0];
  const void* qual = d_in[1];
  const int* mask = (const int*)d_in[2];
  const void* ln_g = d_in[3];
  const void* ln_b = d_in[4];
  const void* Wp = d_in[5];
  const void* bp = d_in[6];
  const void* Wc = d_in[7];
  const void* bc = d_in[8];
  const void* Wq = d_in[9];
  const void* bq = d_in[10];
  const void* Wmw = d_in[11];
  const void* bmw = d_in[12];
  const void* Wmc = d_in[13];
  const void* bmc = d_in[14];
  const void* Wow = d_in[15];
  const void* bow = d_in[16];
  const void* Woc = d_in[17];
  const void* boc = d_in[18];
  const void* Wrw = d_in[19];
  const void* brw = d_in[20];
  const void* Wrc = d_in[21];
  const void* brc = d_in[22];
  const void* Wo = d_in[23];
  const void* bo = d_in[24];

  char* wsb = (char*)d_ws;
  size_t off = 0;
  u16* hist = (u16*)(wsb + off); off += (size_t)BS * 1536 * 2;  // 192MB
  u16* hid = (u16*)(wsb + off); off += (size_t)BS * 512 * 2;    // 64MB
  u16* qe = (u16*)(wsb + off); off += (size_t)BS * 512 * 2;     // 64MB
  u16* WpT = (u16*)(wsb + off); off += (size_t)512 * 256 * 2;
  u16* WqT = (u16*)(wsb + off); off += (size_t)512 * 64 * 2;
  u16* WoT = (u16*)(wsb + off); off += (size_t)512 * 1536 * 2;
  unsigned int* ctr = (unsigned int*)(wsb + off); off += 4 * 1024 * 4;
  int* dflag = (int*)(wsb + off); off += 64;
  if (ws_size < off) {
    // distinctive marker (~48.5 in either dtype's low half)
    hipMemsetAsync(d_out, 0x42, (size_t)out_size * 2, stream);
    return;
  }

  // aliases inside hist (dead before seq_kernel's hist use)
  u16* xn = hist;                          // BS*256
  u16* hid0 = hist + (size_t)BS * 256;     // BS*512
  u16* qual_bf = hist + (size_t)BS * 768;  // BS*64

  hipMemsetAsync(ctr, 0, 4 * 1024 * 4, stream);

  detect_kernel<<<1, 64, 0, stream>>>((const u16*)ln_g, dflag);

  ln_kernel<<<BS / 4, 256, 0, stream>>>(seq, ln_g, ln_b, xn, dflag);
  transpose_kernel<<<(256 * 512 + 255) / 256, 256, 0, stream>>>(Wp, WpT, 256, 512, dflag);
  transpose_kernel<<<(64 * 512 + 255) / 256, 256, 0, stream>>>(Wq, WqT, 64, 512, dflag);
  transpose_kernel<<<(1536 * 512 + 255) / 256, 256, 0, stream>>>(Wo, WoT, 1536, 512, dflag);
  cast_kernel<<<(BS * 64 / 8 + 255) / 256, 256, 0, stream>>>(qual, qual_bf, BS * 64, dflag);

  gemm_kernel<<<dim3(4, BS / 128), 256, 0, stream>>>(xn, WpT, bp, nullptr, hid0, 256, dflag, 0);
  conv_kernel<<<BS / 4, 256, 0, stream>>>(hid0, Wc, bc, hid, dflag);
  gemm_kernel<<<dim3(4, BS / 128), 256, 0, stream>>>(qual_bf, WqT, bq, nullptr, qe, 64, dflag, 0);

  // zero-init hist AFTER its alias uses: any residual protocol failure reads 0.0
  hipMemsetAsync(hist, 0, (size_t)BS * 1536 * 2, stream);

  seq_kernel<<<256, 256, 0, stream>>>(hid, qe, mask,
      Wmw, bmw, Wmc, bmc, Wow, bow, Woc, boc, Wrw, brw, Wrc, brc,
      hist, d_out, ctr, dflag);

  gemm_kernel<<<dim3(4, BS / 128), 256, 0, stream>>>(hist, WoT, bo, hid, d_out, 1536, dflag, 1);
}

// Round 4
// 4362.429 us; speedup vs baseline: 3.1757x; 3.1757x over previous
//
#include <hip/hip_runtime.h>
#include <hip/hip_bf16.h>
#include <cstdint>
#include <cstddef>

#define DEV static __device__ __forceinline__

typedef unsigned short u16;
typedef __attribute__((ext_vector_type(8))) short short8;
typedef __attribute__((ext_vector_type(4))) short short4v;
typedef __attribute__((ext_vector_type(4))) float f32x4;
typedef __attribute__((ext_vector_type(4))) int i32x4;

constexpr int B = 64, S = 1024, DIN = 256, H = 512;
constexpr int BS = B * S;

DEV float b2f(u16 u) { union { unsigned int i; float f; } v; v.i = ((unsigned int)u) << 16; return v.f; }
DEV u16 f2u(float f) {
  __hip_bfloat16 h = __float2bfloat16(f);
  u16 r; __builtin_memcpy(&r, &h, 2); return r;
}
DEV float sigf(float x) { return 1.0f / (1.0f + __expf(-x)); }
// dataset load: isf=1 -> float32, else bf16
DEV float ldf(const void* p, size_t i, int isf) {
  return isf ? ((const float*)p)[i] : b2f(((const u16*)p)[i]);
}

DEV void gload_lds16(const void* g, void* l) {
  __builtin_amdgcn_global_load_lds(
      (const __attribute__((address_space(1))) unsigned int*)g,
      (__attribute__((address_space(3))) unsigned int*)l, 16, 0, 0);
}

// coherent (cache-bypass) 16B load: reads at the L3/coherence point
DEV i32x4 cload16(const void* g) {
  i32x4 v;
  asm volatile("global_load_dwordx4 %0, %1, off sc0 sc1" : "=v"(v) : "v"(g));
  return v;
}

// ---------------- dtype detect: ln_g[0]==1.0; f32 -> low u16 is 0 ----------------
__global__ void detect_kernel(const u16* __restrict__ g, int* __restrict__ flag) {
  if (threadIdx.x == 0) flag[0] = (g[0] == (u16)0) ? 1 : 0;
}

// ---------------- LayerNorm: xn = LN(seq)*g + b (bf16 out) ----------------
__global__ __launch_bounds__(256) void ln_kernel(const void* __restrict__ x,
    const void* __restrict__ gw, const void* __restrict__ bw, u16* __restrict__ xn,
    const int* __restrict__ dfl) {
  int isf = dfl[0];
  int tid = threadIdx.x, lane = tid & 63, wid = tid >> 6;
  size_t t = (size_t)blockIdx.x * 4 + wid;  // token
  float f[4];
  if (isf) {
    f32x4 v = *(const f32x4*)((const float*)x + t * DIN + lane * 4);
#pragma unroll
    for (int j = 0; j < 4; j++) f[j] = v[j];
  } else {
    short4v v = *(const short4v*)((const u16*)x + t * DIN + lane * 4);
#pragma unroll
    for (int j = 0; j < 4; j++) f[j] = b2f((u16)v[j]);
  }
  float s0 = f[0] + f[1] + f[2] + f[3];
  float s1 = f[0]*f[0] + f[1]*f[1] + f[2]*f[2] + f[3]*f[3];
#pragma unroll
  for (int off = 32; off; off >>= 1) { s0 += __shfl_xor(s0, off); s1 += __shfl_xor(s1, off); }
  float mu = s0 * (1.0f / DIN);
  float var = s1 * (1.0f / DIN) - mu * mu;
  float rs = rsqrtf(var + 1e-5f);
  short4v o;
#pragma unroll
  for (int j = 0; j < 4; j++) {
    float xv = (f[j] - mu) * rs * ldf(gw, lane*4 + j, isf) + ldf(bw, lane*4 + j, isf);
    o[j] = (short)f2u(xv);
  }
  *(short4v*)(xn + t * DIN + lane * 4) = o;
}

// ---------------- transpose (K,N) -> (N,K), dataset in -> bf16 out ----------------
__global__ void transpose_kernel(const void* __restrict__ in, u16* __restrict__ out,
                                 int R, int C, const int* __restrict__ dfl) {
  int isf = dfl[0];
  int idx = blockIdx.x * 256 + threadIdx.x;
  if (idx >= R * C) return;
  int r = idx / C, c = idx - r * C;
  out[(size_t)c * R + r] = isf ? f2u(((const float*)in)[idx]) : ((const u16*)in)[idx];
}

// ---------------- dataset -> bf16 cast (8 elems/thread) ----------------
__global__ __launch_bounds__(256) void cast_kernel(const void* __restrict__ in,
    u16* __restrict__ out, int n, const int* __restrict__ dfl) {
  int isf = dfl[0];
  int i0 = (blockIdx.x * 256 + threadIdx.x) * 8;
  if (i0 >= n) return;
  short8 o;
  if (isf) {
    f32x4 a = *(const f32x4*)((const float*)in + i0);
    f32x4 b = *(const f32x4*)((const float*)in + i0 + 4);
#pragma unroll
    for (int j = 0; j < 4; j++) { o[j] = (short)f2u(a[j]); o[j+4] = (short)f2u(b[j]); }
  } else {
    o = *(const short8*)((const u16*)in + i0);
  }
  *(short8*)(out + i0) = o;
}

// ---------------- depthwise conv3 along S + bc ----------------
__global__ __launch_bounds__(256) void conv_kernel(const u16* __restrict__ h0,
    const void* __restrict__ Wc, const void* __restrict__ bc, u16* __restrict__ hid,
    const int* __restrict__ dfl) {
  int isf = dfl[0];
  int tid = threadIdx.x;
  size_t token = (size_t)blockIdx.x * 4 + (tid >> 6);
  int lane = tid & 63;
  int s = (int)(token & (size_t)(S - 1));
  int hh = lane * 8;
  const u16* pm = h0 + token * H + hh;
  short8 vm = *(const short8*)pm;
  short8 vp = {0,0,0,0,0,0,0,0}, vn = {0,0,0,0,0,0,0,0};
  if (s > 0) vp = *(const short8*)(pm - H);
  if (s < S - 1) vn = *(const short8*)(pm + H);
  float w[24];
#pragma unroll
  for (int j = 0; j < 24; j++) w[j] = ldf(Wc, (size_t)hh * 3 + j, isf);
  short8 vo;
#pragma unroll
  for (int i = 0; i < 8; i++) {
    float acc = ldf(bc, hh + i, isf);
    acc += b2f((u16)vp[i]) * w[i*3 + 0];
    acc += b2f((u16)vm[i]) * w[i*3 + 1];
    acc += b2f((u16)vn[i]) * w[i*3 + 2];
    vo[i] = (short)f2u(acc);
  }
  *(short8*)(hid + token * H + hh) = vo;
}

// ---------------- generic MFMA GEMM: C(BSx512) = A(BSxK) @ Bt^T, +bias(+res) ----------------
DEV int swz(int row, int kbyte) { return row * 128 + (kbyte ^ ((row & 7) << 4)); }

__global__ __launch_bounds__(256) void gemm_kernel(
    const u16* __restrict__ A, const u16* __restrict__ Bt,
    const void* __restrict__ bias, const u16* __restrict__ res,
    void* __restrict__ C, int K, const int* __restrict__ dfl, int out_ds) {
  int isf = dfl[0];
  __shared__ __align__(16) char sA[128 * 64 * 2];
  __shared__ __align__(16) char sB[128 * 64 * 2];
  int tid = threadIdx.x, lane = tid & 63, wid = tid >> 6;
  int wr = wid >> 1, wc = wid & 1;
  int m0 = blockIdx.y * 128, n0 = blockIdx.x * 128;
  f32x4 zf = {0.f, 0.f, 0.f, 0.f};
  f32x4 acc[4][4];
#pragma unroll
  for (int a = 0; a < 4; a++)
#pragma unroll
    for (int b = 0; b < 4; b++) acc[a][b] = zf;
  int nsteps = K >> 6;
  for (int kt = 0; kt < nsteps; kt++) {
    int k0 = kt << 6;
    __syncthreads();
#pragma unroll
    for (int ri = 0; ri < 4; ri++) {
      int ci = ri * 256 + tid;
      int row = ci >> 3, kc = ci & 7;
      *(short8*)(sA + swz(row, kc * 16)) = *(const short8*)(A + (size_t)(m0 + row) * K + k0 + kc * 8);
      *(short8*)(sB + swz(row, kc * 16)) = *(const short8*)(Bt + (size_t)(n0 + row) * K + k0 + kc * 8);
    }
    __syncthreads();
#pragma unroll
    for (int kk = 0; kk < 2; kk++) {
      int kb = (kk * 32 + ((lane >> 4) * 8)) * 2;
      short8 af[4], bf[4];
#pragma unroll
      for (int t = 0; t < 4; t++) af[t] = *(const short8*)(sA + swz(wr * 64 + t * 16 + (lane & 15), kb));
#pragma unroll
      for (int t = 0; t < 4; t++) bf[t] = *(const short8*)(sB + swz(wc * 64 + t * 16 + (lane & 15), kb));
#pragma unroll
      for (int tr = 0; tr < 4; tr++)
#pragma unroll
        for (int tc = 0; tc < 4; tc++)
          acc[tr][tc] = __builtin_amdgcn_mfma_f32_16x16x32_bf16(af[tr], bf[tc], acc[tr][tc], 0, 0, 0);
    }
  }
#pragma unroll
  for (int tr = 0; tr < 4; tr++) {
#pragma unroll
    for (int tc = 0; tc < 4; tc++) {
      int n = n0 + wc * 64 + tc * 16 + (lane & 15);
      float bv = ldf(bias, n, isf);
#pragma unroll
      for (int jj = 0; jj < 4; jj++) {
        int m = m0 + wr * 64 + tr * 16 + ((lane >> 4) * 4) + jj;
        size_t idx = (size_t)m * 512 + n;
        float v = acc[tr][tc][jj] + bv;
        if (res) v += b2f(res[idx]);
        if (out_ds && isf) ((float*)C)[idx] = v;
        else ((u16*)C)[idx] = f2u(v);
      }
    }
  }
}

// ---------------- persistent sequential recurrence ----------------
// grid 256 = 4 rowgroups(16 batch rows) x 64 colblocks(8 cols of H)
__global__ __launch_bounds__(256, 1) void seq_kernel(
    const u16* __restrict__ hid, const u16* __restrict__ qe, const int* __restrict__ mask,
    const void* __restrict__ Wmw, const void* __restrict__ bmw,
    const void* __restrict__ Wmc, const void* __restrict__ bmc,
    const void* __restrict__ Wow, const void* __restrict__ bow,
    const void* __restrict__ Woc, const void* __restrict__ boc,
    const void* __restrict__ Wrw, const void* __restrict__ brw,
    const void* __restrict__ Wrc, const void* __restrict__ brc,
    u16* __restrict__ hist, void* __restrict__ dout, unsigned int* __restrict__ ctr,
    const int* __restrict__ dfl) {

  constexpr int PITCHA = (1024 + 8) * 2;   // x,q rows (bytes)
  constexpr int PITCHB = (1536 + 8) * 2;   // m,o,r rows (bytes)
  constexpr int RED_OFF = 49408;
  constexpr int ST_OFF = RED_OFF + 12288;
  constexpr int BIAS_OFF = ST_OFF + 1536;
  constexpr int MASK_OFF = BIAS_OFF + 192;
  constexpr int DEAD_OFF = MASK_OFF + 64;
  __shared__ __align__(16) char lds_raw[DEAD_OFF + 16];

  float* REDf = (float*)(lds_raw + RED_OFF);
  float* STf = (float*)(lds_raw + ST_OFF);
  float* BIASf = (float*)(lds_raw + BIAS_OFF);
  int* MASKi = (int*)(lds_raw + MASK_OFF);
  int* DEADi = (int*)(lds_raw + DEAD_OFF);

  int isf = dfl[0];
  int tid = threadIdx.x, lane = tid & 63, wid = tid >> 6;
  int g = blockIdx.x >> 6, cb = blockIdx.x & 63;
  int b0 = g * 16, c0 = cb * 8;

  // section -> tiles; tiles: T0=mw|ow, T1=mc|oc, T2=rw|rc ; sections: x,q,m,o,r
  constexpr int NTS[5] = {3, 3, 3, 2, 1};
  constexpr int FBASE[5] = {0, 12, 24, 36, 44};
  constexpr int TLIST[5][3] = { {0,1,2}, {0,1,2}, {0,1,2}, {1,2,0}, {1,0,0} };
  // (tile, sec, half) -> weight selector / row offset ; -1 = zero
  constexpr int WSEL[3][5][2] = {
    { {0,-1}, {0,2}, {-1,2}, {-1,-1}, {-1,-1} },
    { {1,-1}, {1,3}, {-1,3}, {1,-1}, {-1,3} },
    { {-1,5}, {4,-1}, {-1,5}, {4,5}, {-1,-1} },
  };
  constexpr int ROFF[3][5][2] = {
    { {0,0}, {512,0}, {0,512}, {0,0}, {0,0} },
    { {0,0}, {512,0}, {0,512}, {1024,0}, {0,1024} },
    { {0,0}, {0,0}, {0,512}, {512,1024}, {0,0} },
  };

  // ---- load weight B-fragments into VGPRs (once) ----
  short8 wfrag[48];
  {
    int col16 = lane & 15, half = col16 >> 3;
    int coln = c0 + (col16 & 7);
#pragma unroll
    for (int sec = 0; sec < 5; sec++) {
#pragma unroll
      for (int j = 0; j < 4; j++) {
#pragma unroll
        for (int ti = 0; ti < 3; ti++) {
          if (ti >= NTS[sec]) continue;
          const int tile = TLIST[sec][ti];
          int wsel = WSEL[tile][sec][half];
          int ro = ROFF[tile][sec][half];
          const void* wp = (wsel == 0) ? Wmw : (wsel == 1) ? Wmc : (wsel == 2) ? Wow
                         : (wsel == 3) ? Woc : (wsel == 4) ? Wrw : Wrc;
          short8 f8;
#pragma unroll
          for (int jj = 0; jj < 8; jj++) {
            int kin = (j * 4 + wid) * 32 + ((lane >> 4) * 8) + jj;
            u16 v = 0;
            if (wsel >= 0) v = f2u(ldf(wp, (size_t)(ro + kin) * 512 + coln, isf));
            f8[jj] = (short)v;
          }
          wfrag[FBASE[sec] + j * NTS[sec] + ti] = f8;
        }
      }
    }
  }
  // biases (order mw,mc,ow,oc,rw,rc) and state init
  if (tid < 48) {
    int gate = tid >> 3, col = tid & 7;
    const void* bp_ = (gate == 0) ? bmw : (gate == 1) ? bmc : (gate == 2) ? bow
                    : (gate == 3) ? boc : (gate == 4) ? brw : brc;
    BIASf[tid] = ldf(bp_, c0 + col, isf);
  }
  if (tid < 128) { STf[tid*3] = 0.f; STf[tid*3+1] = 0.f; STf[tid*3+2] = 0.f; }
  if (tid == 0) DEADi[0] = 0;
  __syncthreads();

  bool dead = false;
  for (int s = 0; s < S; s++) {
    // ---- Phase A: stage x,q (no cross-block dependency) ----
    {
      int r0 = wid * 4;
#pragma unroll
      for (int rr = 0; rr < 4; rr++) {
        int b = b0 + r0 + rr;
        const u16* gx = hid + ((size_t)b * S + s) * H;
        const u16* gq = qe + ((size_t)b * S + s) * H;
        char* lx = lds_raw + (size_t)(r0 + rr) * PITCHA;
        gload_lds16(gx + lane * 8, lx);
        gload_lds16(gq + lane * 8, lx + 1024);
      }
    }
    if (tid < 16) MASKi[tid] = mask[(size_t)(b0 + tid) * S + s];
    asm volatile("s_waitcnt vmcnt(0)" ::: "memory");
    __syncthreads();  // bar1: x,q staged

    f32x4 zf = {0.f, 0.f, 0.f, 0.f};
    f32x4 acc[3]; acc[0] = zf; acc[1] = zf; acc[2] = zf;

    // ---- Phase A MFMA: sections x,q (overlaps the cross-block wait) ----
#pragma unroll
    for (int sec = 0; sec < 2; sec++) {
#pragma unroll
      for (int j = 0; j < 4; j++) {
        const short8 a = *(const short8*)(lds_raw + (size_t)(lane & 15) * PITCHA + sec * 1024 +
                                          ((j * 4 + wid) * 32 + ((lane >> 4) * 8)) * 2);
#pragma unroll
        for (int ti = 0; ti < 3; ti++) {
          if (ti >= NTS[sec]) continue;
          const int tile = TLIST[sec][ti];
          acc[tile] = __builtin_amdgcn_mfma_f32_16x16x32_bf16(a, wfrag[FBASE[sec] + j * NTS[sec] + ti], acc[tile], 0, 0, 0);
        }
      }
    }

    // ---- wait for step s-1 states (relaxed poll; no fences, no cache maintenance) ----
    if (tid == 0 && s > 0 && !dead) {
      unsigned int it = 0;
      while (__hip_atomic_load(&ctr[g * S + s - 1], __ATOMIC_RELAXED, __HIP_MEMORY_SCOPE_AGENT) < 64u) {
        if (++it > (1u << 22)) { dead = true; DEADi[0] = 1; break; }
      }
    }
    __syncthreads();  // bar2: A-region reads done AND prev states published

    // ---- Phase B: stage m,o,r via coherent (sc0 sc1) loads -> LDS ----
    if (s == 0) {
      short8 z8 = {0,0,0,0,0,0,0,0};
#pragma unroll
      for (int rr = 0; rr < 4; rr++) {
        char* lr = lds_raw + (size_t)(wid * 4 + rr) * PITCHB;
#pragma unroll
        for (int sc = 0; sc < 3; sc++)
          *(short8*)(lr + sc * 1024 + lane * 16) = z8;
      }
    } else {
      i32x4 v[12];
#pragma unroll
      for (int rr = 0; rr < 4; rr++) {
        int b = b0 + wid * 4 + rr;
        const char* gm = (const char*)(hist + ((size_t)b * S + (s - 1)) * 1536);
#pragma unroll
        for (int sc = 0; sc < 3; sc++)
          v[rr * 3 + sc] = cload16(gm + sc * 1024 + lane * 16);
      }
      asm volatile("s_waitcnt vmcnt(0)" ::: "memory");
#pragma unroll
      for (int rr = 0; rr < 4; rr++) {
        char* lr = lds_raw + (size_t)(wid * 4 + rr) * PITCHB;
#pragma unroll
        for (int sc = 0; sc < 3; sc++)
          *(i32x4*)(lr + sc * 1024 + lane * 16) = v[rr * 3 + sc];
      }
    }
    __syncthreads();  // bar3: m,o,r staged

    // ---- Phase B MFMA: sections m,o,r ----
#pragma unroll
    for (int sec = 2; sec < 5; sec++) {
#pragma unroll
      for (int j = 0; j < 4; j++) {
        const short8 a = *(const short8*)(lds_raw + (size_t)(lane & 15) * PITCHB + (sec - 2) * 1024 +
                                          ((j * 4 + wid) * 32 + ((lane >> 4) * 8)) * 2);
#pragma unroll
        for (int ti = 0; ti < 3; ti++) {
          if (ti >= NTS[sec]) continue;
          const int tile = TLIST[sec][ti];
          acc[tile] = __builtin_amdgcn_mfma_f32_16x16x32_bf16(a, wfrag[FBASE[sec] + j * NTS[sec] + ti], acc[tile], 0, 0, 0);
        }
      }
    }
    // dump partials (lane-major)
#pragma unroll
    for (int t = 0; t < 3; t++)
      *(f32x4*)(REDf + (wid * 3 + t) * 256 + lane * 4) = acc[t];
    __syncthreads();  // bar4: partials in LDS

    // ---- finalize: reduce partials, gates, state update, publish bf16 ----
    if (tid < 128) {
      int row = tid >> 3, col = tid & 7;
      int lbase = ((row >> 2) * 16) * 4 + (row & 3);
      auto rd = [&](int tile, int col16) {
        int e = lbase + col16 * 4;
        return REDf[(0 * 3 + tile) * 256 + e] + REDf[(1 * 3 + tile) * 256 + e] +
               REDf[(2 * 3 + tile) * 256 + e] + REDf[(3 * 3 + tile) * 256 + e];
      };
      float pmw = rd(0, col)     + BIASf[0 * 8 + col];
      float pmc = rd(1, col)     + BIASf[1 * 8 + col];
      float pow_ = rd(0, col + 8) + BIASf[2 * 8 + col];
      float poc = rd(1, col + 8) + BIASf[3 * 8 + col];
      float prw = rd(2, col)     + BIASf[4 * 8 + col];
      float prc = rd(2, col + 8) + BIASf[5 * 8 + col];
      float mwv = sigf(pmw), mcv = tanhf(pmc);
      float owv = sigf(pow_), ocv = tanhf(poc);
      float rwv = sigf(prw), rcv = tanhf(prc);
      float* st = STf + (row * 8 + col) * 3;
      float m_ = st[0], o_ = st[1], r_ = st[2];
      bool v = MASKi[row] > 0;
      float nm = v ? (1.f - mwv) * m_ + mwv * mcv : m_;
      float no = v ? (1.f - owv) * o_ + owv * ocv : o_;
      float nr = v ? (1.f - rwv) * r_ + rwv * rcv : r_;
      if (DEADi[0]) { nm = 12345.0f; no = 12345.0f; nr = 12345.0f; }  // deadlock marker
      st[0] = nm; st[1] = no; st[2] = nr;
      size_t hb = ((size_t)(b0 + row) * S + s) * 1536 + c0 + col;
      // write-through (sc0 sc1): visible at coherence point once vmcnt retires
      __hip_atomic_store(&hist[hb], f2u(nm), __ATOMIC_RELAXED, __HIP_MEMORY_SCOPE_SYSTEM);
      __hip_atomic_store(&hist[hb + 512], f2u(no), __ATOMIC_RELAXED, __HIP_MEMORY_SCOPE_SYSTEM);
      __hip_atomic_store(&hist[hb + 1024], f2u(nr), __ATOMIC_RELAXED, __HIP_MEMORY_SCOPE_SYSTEM);
    }
    __syncthreads();  // bar5: implicit vmcnt(0) drains every thread's publish stores
    if (tid == 0)
      __hip_atomic_fetch_add(&ctr[g * S + s], 1u, __ATOMIC_RELAXED, __HIP_MEMORY_SCOPE_AGENT);
  }

  // final states -> d_out tail (dataset dtype)
  if (tid < 128) {
    int row = tid >> 3, col = tid & 7;
    float* st = STf + (row * 8 + col) * 3;
    size_t bi = (size_t)(b0 + row) * H + c0 + col;
    size_t obase = (size_t)BS * 512;
    size_t BH = (size_t)B * H;
    if (isf) {
      float* p = (float*)dout;
      p[obase + bi] = st[0]; p[obase + BH + bi] = st[1]; p[obase + 2*BH + bi] = st[2];
    } else {
      u16* p = (u16*)dout;
      p[obase + bi] = f2u(st[0]); p[obase + BH + bi] = f2u(st[1]); p[obase + 2*BH + bi] = f2u(st[2]);
    }
  }
}

extern "C" void kernel_launch(void* const* d_in, const int* in_sizes, int n_in,
                              void* d_out, int out_size, void* d_ws, size_t ws_size,
                              hipStream_t stream) {
  (void)in_sizes; (void)n_in;
  const void* seq = d_in[0];
  const void* qual = d_in[1];
  const int* mask = (const int*)d_in[2];
  const void* ln_g = d_in[3];
  const void* ln_b = d_in[4];
  const void* Wp = d_in[5];
  const void* bp = d_in[6];
  const void* Wc = d_in[7];
  const void* bc = d_in[8];
  const void* Wq = d_in[9];
  const void* bq = d_in[10];
  const void* Wmw = d_in[11];
  const void* bmw = d_in[12];
  const void* Wmc = d_in[13];
  const void* bmc = d_in[14];
  const void* Wow = d_in[15];
  const void* bow = d_in[16];
  const void* Woc = d_in[17];
  const void* boc = d_in[18];
  const void* Wrw = d_in[19];
  const void* brw = d_in[20];
  const void* Wrc = d_in[21];
  const void* brc = d_in[22];
  const void* Wo = d_in[23];
  const void* bo = d_in[24];

  char* wsb = (char*)d_ws;
  size_t off = 0;
  u16* hist = (u16*)(wsb + off); off += (size_t)BS * 1536 * 2;  // 192MB
  u16* hid = (u16*)(wsb + off); off += (size_t)BS * 512 * 2;    // 64MB
  u16* qe = (u16*)(wsb + off); off += (size_t)BS * 512 * 2;     // 64MB
  u16* WpT = (u16*)(wsb + off); off += (size_t)512 * 256 * 2;
  u16* WqT = (u16*)(wsb + off); off += (size_t)512 * 64 * 2;
  u16* WoT = (u16*)(wsb + off); off += (size_t)512 * 1536 * 2;
  unsigned int* ctr = (unsigned int*)(wsb + off); off += 4 * 1024 * 4;
  int* dflag = (int*)(wsb + off); off += 64;
  if (ws_size < off) {
    // distinctive marker (~48.5 in either dtype's low half)
    hipMemsetAsync(d_out, 0x42, (size_t)out_size * 2, stream);
    return;
  }

  // aliases inside hist (dead before seq_kernel's hist use)
  u16* xn = hist;                          // BS*256
  u16* hid0 = hist + (size_t)BS * 256;     // BS*512
  u16* qual_bf = hist + (size_t)BS * 768;  // BS*64

  hipMemsetAsync(ctr, 0, 4 * 1024 * 4, stream);

  detect_kernel<<<1, 64, 0, stream>>>((const u16*)ln_g, dflag);

  ln_kernel<<<BS / 4, 256, 0, stream>>>(seq, ln_g, ln_b, xn, dflag);
  transpose_kernel<<<(256 * 512 + 255) / 256, 256, 0, stream>>>(Wp, WpT, 256, 512, dflag);
  transpose_kernel<<<(64 * 512 + 255) / 256, 256, 0, stream>>>(Wq, WqT, 64, 512, dflag);
  transpose_kernel<<<(1536 * 512 + 255) / 256, 256, 0, stream>>>(Wo, WoT, 1536, 512, dflag);
  cast_kernel<<<(BS * 64 / 8 + 255) / 256, 256, 0, stream>>>(qual, qual_bf, BS * 64, dflag);

  gemm_kernel<<<dim3(4, BS / 128), 256, 0, stream>>>(xn, WpT, bp, nullptr, hid0, 256, dflag, 0);
  conv_kernel<<<BS / 4, 256, 0, stream>>>(hid0, Wc, bc, hid, dflag);
  gemm_kernel<<<dim3(4, BS / 128), 256, 0, stream>>>(qual_bf, WqT, bq, nullptr, qe, 64, dflag, 0);

  seq_kernel<<<256, 256, 0, stream>>>(hid, qe, mask,
      Wmw, bmw, Wmc, bmc, Wow, bow, Woc, boc, Wrw, brw, Wrc, brc,
      hist, d_out, ctr, dflag);

  gemm_kernel<<<dim3(4, BS / 128), 256, 0, stream>>>(hist, WoT, bo, hid, d_out, 1536, dflag, 1);
}